// Round 1
// baseline (98.505 us; speedup 1.0000x reference)
//
#include <hip/hip_runtime.h>

// CorrelationMSELoss: out = mean((pred-label)^2)
//                         + sum_rows( branch(s_pos, s_neg, n_one, n_zero) )
// pred, label: [8192, 1024] fp32. label in {0,1} exactly.
// s_zero = e^-1 * s_neg (labels binary), n_zero = L - n_one.

#define B_ROWS 8192
#define L_COLS 1024

__device__ __forceinline__ void wave_reduce4(float& a, float& b, float& c, float& d) {
    #pragma unroll
    for (int off = 32; off >= 1; off >>= 1) {
        a += __shfl_down(a, off, 64);
        b += __shfl_down(b, off, 64);
        c += __shfl_down(c, off, 64);
        d += __shfl_down(d, off, 64);
    }
}

// One block per row; 256 threads x float4 = 1024 elements.
__global__ __launch_bounds__(256) void corr_row_kernel(
        const float4* __restrict__ pred4,
        const float4* __restrict__ label4,
        float* __restrict__ row_out) {
    const int row = blockIdx.x;
    const int idx = row * (L_COLS / 4) + threadIdx.x;

    const float4 p = pred4[idx];
    const float4 l = label4[idx];

    float mse = 0.f, sp = 0.f, sn = 0.f, cnt = 0.f;

    {
        float d = p.x - l.x; mse += d * d;
        const bool pos = l.x > 0.f;
        const float e = __expf(p.x), ei = __expf(-p.x);
        sp += pos ? ei : 0.f; sn += pos ? 0.f : e; cnt += pos ? 1.f : 0.f;
    }
    {
        float d = p.y - l.y; mse += d * d;
        const bool pos = l.y > 0.f;
        const float e = __expf(p.y), ei = __expf(-p.y);
        sp += pos ? ei : 0.f; sn += pos ? 0.f : e; cnt += pos ? 1.f : 0.f;
    }
    {
        float d = p.z - l.z; mse += d * d;
        const bool pos = l.z > 0.f;
        const float e = __expf(p.z), ei = __expf(-p.z);
        sp += pos ? ei : 0.f; sn += pos ? 0.f : e; cnt += pos ? 1.f : 0.f;
    }
    {
        float d = p.w - l.w; mse += d * d;
        const bool pos = l.w > 0.f;
        const float e = __expf(p.w), ei = __expf(-p.w);
        sp += pos ? ei : 0.f; sn += pos ? 0.f : e; cnt += pos ? 1.f : 0.f;
    }

    wave_reduce4(mse, sp, sn, cnt);

    __shared__ float smem[4][4];
    const int wave = threadIdx.x >> 6;
    const int lane = threadIdx.x & 63;
    if (lane == 0) {
        smem[wave][0] = mse; smem[wave][1] = sp;
        smem[wave][2] = sn;  smem[wave][3] = cnt;
    }
    __syncthreads();

    if (threadIdx.x == 0) {
        float tm = 0.f, tp = 0.f, tn = 0.f, tc = 0.f;
        #pragma unroll
        for (int w = 0; w < 4; ++w) {
            tm += smem[w][0]; tp += smem[w][1];
            tn += smem[w][2]; tc += smem[w][3];
        }
        const float n_one  = tc;
        const float n_zero = (float)L_COLS - tc;

        float row_loss;
        if (n_one == 0.f) {
            // all-zero row: s_zero / max(n_zero,1), s_zero = e^-1 * s_neg
            row_loss = tn * 0.36787944117144233f / fmaxf(n_zero, 1.f);
        } else if (n_zero == 0.f) {
            row_loss = tp / fmaxf(n_one, 1.f);
        } else {
            row_loss = tp * tn / (n_one * n_zero);
        }
        // fold this row's MSE contribution: sum_sq / (B*L)
        row_out[row] = row_loss + tm * (1.0f / ((float)B_ROWS * (float)L_COLS));
    }
}

// Single-block final reduction of 8192 per-row values -> scalar.
__global__ __launch_bounds__(256) void corr_final_reduce(
        const float* __restrict__ row_vals, float* __restrict__ out) {
    float s = 0.f;
    for (int i = threadIdx.x; i < B_ROWS; i += 256) s += row_vals[i];

    #pragma unroll
    for (int off = 32; off >= 1; off >>= 1) s += __shfl_down(s, off, 64);

    __shared__ float sm[4];
    const int wave = threadIdx.x >> 6;
    const int lane = threadIdx.x & 63;
    if (lane == 0) sm[wave] = s;
    __syncthreads();
    if (threadIdx.x == 0) out[0] = sm[0] + sm[1] + sm[2] + sm[3];
}

extern "C" void kernel_launch(void* const* d_in, const int* in_sizes, int n_in,
                              void* d_out, int out_size, void* d_ws, size_t ws_size,
                              hipStream_t stream) {
    const float4* pred4  = (const float4*)d_in[0];
    const float4* label4 = (const float4*)d_in[1];
    float* out = (float*)d_out;
    float* ws  = (float*)d_ws;   // 8192 floats = 32 KB of scratch

    corr_row_kernel<<<B_ROWS, 256, 0, stream>>>(pred4, label4, ws);
    corr_final_reduce<<<1, 256, 0, stream>>>(ws, out);
}

// Round 3
// 92.316 us; speedup vs baseline: 1.0670x; 1.0670x over previous
//
#include <hip/hip_runtime.h>

// CorrelationMSELoss: out = mean((pred-label)^2) + sum_rows(branch(...))
// pred, label: [8192, 1024] fp32, label in {0,1} exactly.
//
// Per-element trick (label binary): e = exp2(p * (1-2l)*log2e)
//   => e = exp(-p) for positive labels, exp(+p) for negatives, ONE v_exp_f32.
// sum_e  = sum(e)          ; sum_el = sum(l*e) = s_pos
// s_neg  = sum_e - sum_el  ; s_zero = e^-1 * s_neg ; n_zero = L - n_one.

#define B_ROWS 8192
#define L_COLS 1024
#define LOG2E 1.44269504088896340736f

__device__ __forceinline__ void wave_reduce4(float& a, float& b, float& c, float& d) {
    #pragma unroll
    for (int off = 32; off >= 1; off >>= 1) {
        a += __shfl_down(a, off, 64);
        b += __shfl_down(b, off, 64);
        c += __shfl_down(c, off, 64);
        d += __shfl_down(d, off, 64);
    }
}

__device__ __forceinline__ void accum_elem(float p, float l,
                                           float& mse, float& se, float& sel, float& cnt) {
    const float s = fmaf(l, -2.0f * LOG2E, LOG2E);   // +log2e (l=0) / -log2e (l=1)
    const float e = __builtin_amdgcn_exp2f(s * p);   // v_exp_f32: exp(+p) neg, exp(-p) pos
    se  += e;
    sel  = fmaf(e, l, sel);                          // s_pos partial
    cnt += l;                                        // n_one partial (l is exactly 0/1)
    const float d = p - l;
    mse  = fmaf(d, d, mse);
}

// 4 waves/block, one ROW per WAVE. Each lane: 4 float4 of pred + 4 of label.
// No LDS, no __syncthreads — wave-private shuffle reduce only.
__global__ __launch_bounds__(256) void corr_row_kernel(
        const float4* __restrict__ pred4,
        const float4* __restrict__ label4,
        float* __restrict__ row_out) {
    const int wave = threadIdx.x >> 6;
    const int lane = threadIdx.x & 63;
    const int row  = blockIdx.x * 4 + wave;

    float mse = 0.f, se = 0.f, sel = 0.f, cnt = 0.f;

    const int base = row * (L_COLS / 4);
    #pragma unroll
    for (int k = 0; k < 4; ++k) {
        const int idx = base + k * 64 + lane;   // coalesced: consecutive lanes, consecutive float4
        const float4 p = pred4[idx];
        const float4 l = label4[idx];
        accum_elem(p.x, l.x, mse, se, sel, cnt);
        accum_elem(p.y, l.y, mse, se, sel, cnt);
        accum_elem(p.z, l.z, mse, se, sel, cnt);
        accum_elem(p.w, l.w, mse, se, sel, cnt);
    }

    wave_reduce4(mse, se, sel, cnt);

    if (lane == 0) {
        const float s_pos  = sel;
        const float s_neg  = se - sel;
        const float n_one  = cnt;
        const float n_zero = (float)L_COLS - cnt;

        float row_loss;
        if (n_one == 0.f) {
            row_loss = s_neg * 0.36787944117144233f / fmaxf(n_zero, 1.f);  // s_zero/n_zero
        } else if (n_zero == 0.f) {
            row_loss = s_pos / n_one;
        } else {
            row_loss = s_pos * s_neg / (n_one * n_zero);
        }
        row_out[row] = row_loss + mse * (1.0f / ((float)B_ROWS * (float)L_COLS));
    }
}

// Single-block final reduction of 8192 per-row values -> scalar (float4 loads).
__global__ __launch_bounds__(256) void corr_final_reduce(
        const float4* __restrict__ row_vals4, float* __restrict__ out) {
    float s = 0.f;
    #pragma unroll
    for (int k = 0; k < (B_ROWS / 4) / 256; ++k) {
        const float4 v = row_vals4[k * 256 + threadIdx.x];
        s += (v.x + v.y) + (v.z + v.w);
    }

    #pragma unroll
    for (int off = 32; off >= 1; off >>= 1) s += __shfl_down(s, off, 64);

    __shared__ float sm[4];
    const int wave = threadIdx.x >> 6;
    const int lane = threadIdx.x & 63;
    if (lane == 0) sm[wave] = s;
    __syncthreads();
    if (threadIdx.x == 0) out[0] = (sm[0] + sm[1]) + (sm[2] + sm[3]);
}

extern "C" void kernel_launch(void* const* d_in, const int* in_sizes, int n_in,
                              void* d_out, int out_size, void* d_ws, size_t ws_size,
                              hipStream_t stream) {
    const float4* pred4  = (const float4*)d_in[0];
    const float4* label4 = (const float4*)d_in[1];
    float* out = (float*)d_out;
    float* ws  = (float*)d_ws;   // 8192 floats = 32 KB scratch

    corr_row_kernel<<<B_ROWS / 4, 256, 0, stream>>>(pred4, label4, ws);
    corr_final_reduce<<<1, 256, 0, stream>>>((const float4*)ws, out);
}